// Round 18
// baseline (1919.835 us; speedup 1.0000x reference)
//
#include <hip/hip_runtime.h>
#include <hip/hip_bf16.h>
#include <float.h>

#define NEG_SLOPE 0.01f
typedef float v2f __attribute__((ext_vector_type(2)));
__device__ __forceinline__ float leaky(float x){ return x >= 0.0f ? x : NEG_SLOPE * x; }

#if !__has_builtin(__builtin_elementwise_fma)
#error "need __builtin_elementwise_fma"
#endif

#define RPT16(M) M(0) M(1) M(2) M(3) M(4) M(5) M(6) M(7) \
                 M(8) M(9) M(10) M(11) M(12) M(13) M(14) M(15)
#define RPT8(M) M(0) M(1) M(2) M(3) M(4) M(5) M(6) M(7)

// ================= shared device bodies (verbatim r15, all proven) =================
#define KNN_INS(bdX, biX) { bool c = cd < bdX; float tf = bdX; int ti = biX; \
    bdX = c ? cd : bdX; biX = c ? ci : biX; cd = c ? tf : cd; ci = c ? ti : ci; }
#define KNN_PROC(r, jj) { \
    float dot = qx * r.x + qy * r.y + qz * r.z; \
    float dcur = qq + r.w - 2.0f * dot; \
    if (dcur < bd7){ \
        float cd = dcur; int ci = (jj); \
        KNN_INS(bd0, bi0); KNN_INS(bd1, bi1); KNN_INS(bd2, bi2); KNN_INS(bd3, bi3); \
        KNN_INS(bd4, bi4); KNN_INS(bd5, bi5); KNN_INS(bd6, bi6); KNN_INS(bd7, bi7); \
    } }

__device__ void dev_knn(int b, int m0, const float* q, int M,
                        const float* ref, int Nr, int* idx_out, float4* sref){
    int tid = threadIdx.x;
    int m = m0 + tid;
    const float* Q = q + (size_t)b * 3 * M;
    const float* R = ref + (size_t)b * 3 * Nr;
    bool valid = (m < M);
    float qx = 0.f, qy = 0.f, qz = 0.f, qq = 0.f;
    if (valid){
        qx = Q[m]; qy = Q[M + m]; qz = Q[2 * M + m];
        qq = qx*qx + qy*qy + qz*qz;
    }
    float bd0 = FLT_MAX, bd1 = FLT_MAX, bd2 = FLT_MAX, bd3 = FLT_MAX;
    float bd4 = FLT_MAX, bd5 = FLT_MAX, bd6 = FLT_MAX, bd7 = FLT_MAX;
    int bi0 = 0, bi1 = 0, bi2 = 0, bi3 = 0, bi4 = 0, bi5 = 0, bi6 = 0, bi7 = 0;
    for (int base = 0; base < Nr; base += 1024){
        int jmax = min(1024, Nr - base);
        for (int j = tid; j < jmax; j += 256){
            float rx = R[base + j], ry = R[Nr + base + j], rz = R[2 * Nr + base + j];
            sref[j] = make_float4(rx, ry, rz, rx*rx + ry*ry + rz*rz);
        }
        __syncthreads();
        for (int j = 0; j < jmax; j += 4){
            float4 r0 = sref[j+0]; float4 r1 = sref[j+1];
            float4 r2 = sref[j+2]; float4 r3 = sref[j+3];
            KNN_PROC(r0, base + j + 0)
            KNN_PROC(r1, base + j + 1)
            KNN_PROC(r2, base + j + 2)
            KNN_PROC(r3, base + j + 3)
        }
        __syncthreads();
    }
    if (valid){
        int* o = idx_out + ((size_t)b * M + m) * 8;
        o[0] = bi0; o[1] = bi1; o[2] = bi2; o[3] = bi3;
        o[4] = bi4; o[5] = bi5; o[6] = bi6; o[7] = bi7;
    }
}

#define RC_DECL(i) float a##i = 0.f;
#define RC_FMA(i)  a##i = fmaf(wc[i], h, fmaf(wg[i], sv, a##i));
#define RC_FIN(i)  a##i = a##i * inv + Pr[(size_t)(i) * n];
#define RC_ST(i)   O[(size_t)(i) * n] = a##i;
#define RC_STPM(i) PO[i] = a##i;

__device__ void dev_res(int b, int j0, int n,
        const float* dmc, const float* pmc, const int* idx,
        const float* wc_, const float* wg_, float* dmo, float* pmo,
        float (*tile)[65]){
    int tid = threadIdx.x, lane = tid & 63, w = tid >> 6;
    const float* PM = pmc + (size_t)b * n * 64;
    const int* ID = idx + ((size_t)b * n + j0) * 8;
    for (int c = 0; c < 16; ++c){
        int jl = w * 16 + c;
        const int* id = ID + jl * 8;
        float v = 0.f;
        #pragma unroll
        for (int k = 0; k < 8; ++k)
            v += leaky(PM[(size_t)id[k] * 64 + lane]);
        tile[jl][lane] = v;
    }
    __syncthreads();
    int j = j0 + lane;
    const float* P = dmc + (size_t)b * 64 * n + j;
    const float* sc = &tile[lane][0];
    RPT16(RC_DECL)
    for (int d = 0; d < 64; ++d){
        float h  = leaky(P[(size_t)d * n]);
        float sv = sc[d];
        const float* wc = wc_ + d * 64 + w * 16;
        const float* wg = wg_ + d * 64 + w * 16;
        RPT16(RC_FMA)
    }
    const float inv = 1.0f / 9.0f;
    const float* Pr = P + (size_t)(w * 16) * n;
    RPT16(RC_FIN)
    float* O = dmo + ((size_t)b * 64 + w * 16) * n + j;
    RPT16(RC_ST)
    float* PO = pmo + ((size_t)b * n + j) * 64 + w * 16;
    RPT16(RC_STPM)
    __syncthreads();
}

__device__ void dev_pool(int b, int m0, int np, int nsrc,
        const float* pmc, const int* idx, float* dmo, float* pmo, float (*tile)[65]){
    int tid = threadIdx.x, lane = tid & 63, w = tid >> 6;
    const float* PM = pmc + (size_t)b * nsrc * 64;
    float* PMO = pmo + (size_t)b * np * 64;
    const int* ID = idx + ((size_t)b * np + m0) * 8;
    for (int c = 0; c < 16; ++c){
        int ml = w * 16 + c;
        const int* id = ID + ml * 8;
        float v = -FLT_MAX;
        #pragma unroll
        for (int k = 0; k < 8; ++k)
            v = fmaxf(v, PM[(size_t)id[k] * 64 + lane]);
        tile[ml][lane] = v;
        PMO[(size_t)(m0 + ml) * 64 + lane] = v;
    }
    __syncthreads();
    float* O = dmo + (size_t)b * 64 * np + m0;
    for (int c = 0; c < 16; ++c){
        int d = w * 16 + c;
        O[(size_t)d * np + lane] = tile[lane][d];
    }
    __syncthreads();
}

__device__ void dev_conv0(int t, const float* xyz, const float* w0,
                          float* dm, float* pm){
    int b = t >> 6;
    int lane = threadIdx.x & 63, w = threadIdx.x >> 6;
    int j = ((t & 63) << 6) + lane;
    const int n = 4096;
    const float* X = xyz + (size_t)b * 3 * n;
    float x = X[j], y = X[n + j], z = X[2 * n + j];
    float* PO = pm + ((size_t)b * n + j) * 64 + w * 16;
    #pragma unroll
    for (int c = 0; c < 16; ++c){
        int oo = w * 16 + c;
        float v = w0[oo*3] * x + w0[oo*3+1] * y + w0[oo*3+2] * z;
        dm[((size_t)b * 64 + oo) * n + j] = v;
        PO[c] = v;
    }
}

// ---- FPS primitives (r15-proven) ----
template<int CTRL>
__device__ __forceinline__ void dpp2(unsigned long long &bp){
    unsigned h = (unsigned)(bp >> 32), l = (unsigned)bp;
    unsigned th = (unsigned)__builtin_amdgcn_update_dpp(0, (int)h, CTRL, 0xF, 0xF, true);
    unsigned tl = (unsigned)__builtin_amdgcn_update_dpp(0, (int)l, CTRL, 0xF, 0xF, true);
    unsigned long long tp = ((unsigned long long)th << 32) | tl;
    bp = tp > bp ? tp : bp;
}
#define DPP_REDUCE2(bp) dpp2<0x111>(bp); dpp2<0x112>(bp); dpp2<0x114>(bp); \
    dpp2<0x118>(bp); dpp2<0x142>(bp); dpp2<0x143>(bp);

#define FPS_DECL(i) v2f px##i, py##i, pz##i, ds##i;
#define FPS_LOAD(i) { int g0 = tid + (2*(i))*T, g1 = g0 + T; \
    px##i = (v2f){X[g0], X[g1]}; py##i = (v2f){X[N+g0], X[N+g1]}; \
    pz##i = (v2f){X[2*N+g0], X[2*N+g1]}; ds##i = (v2f){1e10f, 1e10f}; }
#define FPS_PIN(i) asm volatile("" : "+v"(px##i), "+v"(py##i), "+v"(pz##i));
// dist >= 0 => float bit order == value order; ~gi larger => gi smaller, so
// u64 max == (dist >, tie: idx <) exactly.
#define FPS_UPD(i) { \
    v2f dx = px##i - l2x, dy = py##i - l2y, dz = pz##i - l2z; \
    v2f dd = __builtin_elementwise_fma(dz, dz, __builtin_elementwise_fma(dy, dy, dx*dx)); \
    float n0 = fminf(ds##i.x, dd.x), n1 = fminf(ds##i.y, dd.y); \
    ds##i = (v2f){n0, n1}; \
    unsigned long long c0 = ((unsigned long long)__float_as_uint(n0) << 32) | (unsigned)~(tid + (2*(i))*T); \
    unsigned long long c1 = ((unsigned long long)__float_as_uint(n1) << 32) | (unsigned)~(tid + (2*(i)+1)*T); \
    bp = c0 > bp ? c0 : bp; bp = c1 > bp ? c1 : bp; }

#define FPS_COMBINE(i) \
    int buf_ = (i) & 1; \
    if ((tid & 63) == 63) sred[buf_][tid >> 6] = bp; \
    __syncthreads(); \
    unsigned long long pp = sred[buf_][0]; \
    _Pragma("unroll") \
    for (int k_ = 1; k_ < 4; ++k_){ unsigned long long pk = sred[buf_][k_]; pp = pk > pp ? pk : pp; } \
    int i0 = (int)~(unsigned)pp; \
    float4 wn = sxyz[i0];

#define FPS_SAVE(i) { v2f t_ = ds##i; SV[tid * 16 + 2*(i)] = t_.x; SV[tid * 16 + 2*(i) + 1] = t_.y; }
#define FPS_REST(i) { ds##i = (v2f){SV[tid * 16 + 2*(i)], SV[tid * 16 + 2*(i) + 1]}; }

// ================= LAUNCH 1: fps16 part A [1,512) || knn@4096 || transpose || conv0 =================
__global__ void __launch_bounds__(256, 1)
k_front(const float* __restrict__ xyz_in, const float* __restrict__ w0,
        const float* __restrict__ fn_wc, const float* __restrict__ fn_wg,
        const float* __restrict__ res_wc, const float* __restrict__ res_wg,
        float* __restrict__ wT, float* __restrict__ dm4a, float* __restrict__ pm4a,
        int* __restrict__ idx4, float* __restrict__ xyz1, float* __restrict__ fpssav){
    __shared__ __align__(16) char LB[66560];
    __shared__ unsigned long long sred[2][4];
    int bid = blockIdx.x, tid = threadIdx.x;
    if (bid < 8){
        float4* sxyz = (float4*)LB;
        constexpr int N = 4096, T = 256;
        const float* X = xyz_in + (size_t)bid * 3 * N;
        RPT8(FPS_DECL) RPT8(FPS_LOAD) RPT8(FPS_PIN)
        for (int t = tid; t < N; t += T)
            sxyz[t] = make_float4(X[t], X[N+t], X[2*N+t], 0.f);
        float* NX_ = xyz1 + (size_t)bid * 3 * 1024;
        if (tid == 0){ NX_[0] = X[0]; NX_[1024] = X[N]; NX_[2048] = X[2*N]; }
        v2f l2x = (v2f){X[0], X[0]}, l2y = (v2f){X[N], X[N]}, l2z = (v2f){X[2*N], X[2*N]};
        __syncthreads();
        for (int i = 1; i < 512; ++i){
            unsigned long long bp = 0;
            RPT8(FPS_UPD)
            DPP_REDUCE2(bp)
            FPS_COMBINE(i)
            l2x = (v2f){wn.x, wn.x}; l2y = (v2f){wn.y, wn.y}; l2z = (v2f){wn.z, wn.z};
            if (tid == 0){ NX_[i] = wn.x; NX_[1024 + i] = wn.y; NX_[2048 + i] = wn.z; }
        }
        // save dist state + last selected coords (exact carry -> bit-identical)
        float* SV = fpssav + (size_t)bid * 4160;
        RPT8(FPS_SAVE)
        if (tid == 0){ SV[4096] = l2x.x; SV[4097] = l2y.x; SV[4098] = l2z.x; }
    } else if (bid < 136){
        int u = bid - 8;
        dev_knn(u >> 4, (u & 15) << 8, xyz_in, 4096, xyz_in, 4096, idx4, (float4*)LB);
    } else if (bid < 164){
        int m = bid - 136;
        const float* s;
        if (m < 2) s = fn_wc + (size_t)m * 4096;
        else if (m < 4) s = fn_wg + (size_t)(m - 2) * 4096;
        else if (m < 16) s = res_wc + (size_t)(m - 4) * 4096;
        else s = res_wg + (size_t)(m - 16) * 4096;
        float* o = wT + (size_t)m * 4096;
        for (int t = tid; t < 4096; t += 256){
            int oo = t >> 6, dd = t & 63;
            o[dd * 64 + oo] = s[t];
        }
    } else {
        for (int t = bid - 164; t < 512; t += 64)
            dev_conv0(t, xyz_in, w0, dm4a, pm4a);
    }
}

// ================= LAUNCH 2: fps16 part B [512,1024) || res4096#1 =================
__global__ void __launch_bounds__(256, 1)
k_frontb(const float* __restrict__ xyz_in, const float* __restrict__ wT,
         const float* __restrict__ dm4a, const float* __restrict__ pm4a,
         const int* __restrict__ idx4,
         float* __restrict__ dm4b, float* __restrict__ pm4b,
         float* __restrict__ xyz1, const float* __restrict__ fpssav){
    __shared__ __align__(16) char LB[66560];
    __shared__ unsigned long long sred[2][4];
    int bid = blockIdx.x, tid = threadIdx.x;
    if (bid < 8){
        float4* sxyz = (float4*)LB;
        constexpr int N = 4096, T = 256;
        const float* X = xyz_in + (size_t)bid * 3 * N;
        const float* SV = fpssav + (size_t)bid * 4160;
        RPT8(FPS_DECL) RPT8(FPS_LOAD) RPT8(FPS_PIN)
        RPT8(FPS_REST)
        for (int t = tid; t < N; t += T)
            sxyz[t] = make_float4(X[t], X[N+t], X[2*N+t], 0.f);
        float lx0 = SV[4096], ly0 = SV[4097], lz0 = SV[4098];
        v2f l2x = (v2f){lx0, lx0}, l2y = (v2f){ly0, ly0}, l2z = (v2f){lz0, lz0};
        float* NX_ = xyz1 + (size_t)bid * 3 * 1024;
        __syncthreads();
        for (int i = 512; i < 1024; ++i){
            unsigned long long bp = 0;
            RPT8(FPS_UPD)
            DPP_REDUCE2(bp)
            FPS_COMBINE(i)
            l2x = (v2f){wn.x, wn.x}; l2y = (v2f){wn.y, wn.y}; l2z = (v2f){wn.z, wn.z};
            if (tid == 0){ NX_[i] = wn.x; NX_[1024 + i] = wn.y; NX_[2048 + i] = wn.z; }
        }
    } else {
        for (int t = bid - 8; t < 512; t += 248)
            dev_res(t >> 6, (t & 63) << 6, 4096, dm4a, pm4a, idx4,
                    wT + 0 * 4096, wT + 2 * 4096, dm4b, pm4b, (float (*)[65])LB);
    }
}

// ================= LAUNCH 3: fps4 || res4096#2 || knn(1024,4096) || knn(1024,1024) =================
__global__ void __launch_bounds__(256, 1)
k_mid1(const float* __restrict__ xyz_in, const float* __restrict__ xyz1,
       const float* __restrict__ wT,
       const float* __restrict__ dm4b, const float* __restrict__ pm4b,
       const int* __restrict__ idx4,
       float* __restrict__ dm4a, float* __restrict__ pm4a,
       int* __restrict__ i1024p, int* __restrict__ i1024s,
       float* __restrict__ xyz2){
    __shared__ __align__(16) char LB[16640];
    __shared__ unsigned long long sred[2][4];
    int bid = blockIdx.x, tid = threadIdx.x;
    if (bid < 8){
        // fps4: 1024 -> 256
        float4* sxyz = (float4*)LB;
        constexpr int N = 1024, T = 256;
        const float* X = xyz1 + (size_t)bid * 3 * N;
        FPS_DECL(0) FPS_DECL(1)
        FPS_LOAD(0) FPS_LOAD(1) FPS_PIN(0) FPS_PIN(1)
        for (int t = tid; t < N; t += T)
            sxyz[t] = make_float4(X[t], X[N+t], X[2*N+t], 0.f);
        float* NX_ = xyz2 + (size_t)bid * 3 * 256;
        if (tid == 0){ NX_[0] = X[0]; NX_[256] = X[N]; NX_[512] = X[2*N]; }
        v2f l2x = (v2f){X[0], X[0]}, l2y = (v2f){X[N], X[N]}, l2z = (v2f){X[2*N], X[2*N]};
        __syncthreads();
        for (int i = 1; i < 256; ++i){
            unsigned long long bp = 0;
            FPS_UPD(0) FPS_UPD(1)
            DPP_REDUCE2(bp)
            FPS_COMBINE(i)
            l2x = (v2f){wn.x, wn.x}; l2y = (v2f){wn.y, wn.y}; l2z = (v2f){wn.z, wn.z};
            if (tid == 0){ NX_[i] = wn.x; NX_[256 + i] = wn.y; NX_[512 + i] = wn.z; }
        }
    } else if (bid < 520){
        int t = bid - 8;
        dev_res(t >> 6, (t & 63) << 6, 4096, dm4b, pm4b, idx4,
                wT + 1 * 4096, wT + 3 * 4096, dm4a, pm4a, (float (*)[65])LB);
    } else if (bid < 552){
        int u = bid - 520;
        dev_knn(u >> 2, (u & 3) << 8, xyz1, 1024, xyz_in, 4096, i1024p, (float4*)LB);
    } else {
        int u = bid - 552;
        dev_knn(u >> 2, (u & 3) << 8, xyz1, 1024, xyz1, 1024, i1024s, (float4*)LB);
    }
}

// ================= LAUNCH 4: fps1 || pool1024 || knn(256,1024) || knn(256,256) =================
__global__ void __launch_bounds__(256, 1)
k_mid2(const float* __restrict__ xyz1, const float* __restrict__ xyz2,
       const float* __restrict__ pm4a, const int* __restrict__ i1024p,
       float* __restrict__ dm1a, float* __restrict__ pm1a,
       int* __restrict__ i256p, int* __restrict__ i256s,
       float* __restrict__ xyz3){
    __shared__ __align__(16) char LB[16640];
    __shared__ unsigned long long sred[2][4];
    int bid = blockIdx.x, tid = threadIdx.x;
    if (bid < 8){
        // fps1: 256 -> 64 (1 pt/thread)
        float4* sxyz = (float4*)LB;
        const float* X2 = xyz2 + (size_t)bid * 3 * 256;
        for (int t = tid; t < 256; t += 256)
            sxyz[t] = make_float4(X2[t], X2[256 + t], X2[512 + t], 0.f);
        float s1x = X2[tid], s1y = X2[256 + tid], s1z = X2[512 + tid], s1d = 1e10f;
        asm volatile("" : "+v"(s1x), "+v"(s1y), "+v"(s1z));
        float* NX_ = xyz3 + (size_t)bid * 3 * 64;
        if (tid == 0){ NX_[0] = X2[0]; NX_[64] = X2[256]; NX_[128] = X2[512]; }
        float lx = X2[0], ly = X2[256], lz = X2[512];
        __syncthreads();
        for (int i = 1; i < 64; ++i){
            float dx = s1x - lx, dy = s1y - ly, dz = s1z - lz;
            float dd = fmaf(dz, dz, fmaf(dy, dy, dx*dx));
            float nd = fminf(s1d, dd); s1d = nd;
            unsigned long long bp = ((unsigned long long)__float_as_uint(nd) << 32) | (unsigned)~tid;
            DPP_REDUCE2(bp)
            FPS_COMBINE(i)
            lx = wn.x; ly = wn.y; lz = wn.z;
            if (tid == 0){ NX_[i] = wn.x; NX_[64 + i] = wn.y; NX_[128 + i] = wn.z; }
        }
    } else if (bid < 136){
        int u = bid - 8;
        dev_pool(u >> 4, (u & 15) << 6, 1024, 4096, pm4a, i1024p,
                 dm1a, pm1a, (float (*)[65])LB);
    } else if (bid < 144){
        dev_knn(bid - 136, 0, xyz2, 256, xyz1, 1024, i256p, (float4*)LB);
    } else {
        dev_knn(bid - 144, 0, xyz2, 256, xyz2, 256, i256s, (float4*)LB);
    }
}

// ================= LAUNCH 5: res1024#1 || knn(64,256) || knn(64,64) =================
__global__ void __launch_bounds__(256, 1)
k_mid3(const float* __restrict__ xyz2, const float* __restrict__ xyz3,
       const float* __restrict__ dm1a, const float* __restrict__ pm1a,
       const int* __restrict__ i1024s, const float* __restrict__ wT,
       float* __restrict__ dm1b, float* __restrict__ pm1b,
       int* __restrict__ i64p, int* __restrict__ i64s){
    __shared__ __align__(16) char LB[16640];
    int bid = blockIdx.x;
    if (bid < 128){
        dev_res(bid >> 4, (bid & 15) << 6, 1024, dm1a, pm1a, i1024s,
                wT + 4 * 4096, wT + 16 * 4096, dm1b, pm1b, (float (*)[65])LB);
    } else if (bid < 136){
        dev_knn(bid - 128, 0, xyz3, 64, xyz2, 256, i64p, (float4*)LB);
    } else {
        dev_knn(bid - 136, 0, xyz3, 64, xyz3, 64, i64s, (float4*)LB);
    }
}

// ================= generic res / pool launches =================
__global__ void __launch_bounds__(256, 1)
k_res_g(const float* __restrict__ dmc, const float* __restrict__ pmc,
        const int* __restrict__ idx, const float* __restrict__ wc_,
        const float* __restrict__ wg_, float* __restrict__ dmo,
        float* __restrict__ pmo, int n){
    __shared__ float tile[64][65];
    int tiles = n >> 6;
    int b = blockIdx.x / tiles, j0 = (blockIdx.x % tiles) << 6;
    dev_res(b, j0, n, dmc, pmc, idx, wc_, wg_, dmo, pmo, tile);
}

__global__ void __launch_bounds__(256, 1)
k_pool_g(const float* __restrict__ pmc, const int* __restrict__ idx,
         float* __restrict__ dmo, float* __restrict__ pmo, int np, int nsrc){
    __shared__ float tile[64][65];
    int tiles = np >> 6;
    int b = blockIdx.x / tiles, m0 = (blockIdx.x % tiles) << 6;
    dev_pool(b, m0, np, nsrc, pmc, idx, dmo, pmo, tile);
}

// ================= tail: pool64 + 4x res64 (in-LDS) + final, 1 block/batch =================
#define RC_FINL64(i) a##i = a##i * inv + pmX[lane][w16 + (i)];
#define RC_WL64(i)   pmX[lane][w16 + (i)] = a##i;

__device__ __forceinline__ void res_lds64g(float (*pmX)[65], float (*S)[65],
        const int* idg, const float* __restrict__ wcT, const float* __restrict__ wgT,
        int lane, int w){
    for (int c = 0; c < 16; ++c){
        int col = w * 16 + c;
        const int* id = idg + col * 8;
        float v = 0.f;
        #pragma unroll
        for (int k = 0; k < 8; ++k) v += leaky(pmX[id[k]][lane]);
        S[col][lane] = v;
    }
    __syncthreads();
    int w16 = w * 16;
    RPT16(RC_DECL)
    #pragma unroll 2
    for (int d = 0; d < 64; ++d){
        float h  = leaky(pmX[lane][d]);
        float sv = S[lane][d];
        const float* wc = wcT + d * 64 + w16;
        const float* wg = wgT + d * 64 + w16;
        RPT16(RC_FMA)
    }
    const float inv = 1.0f / 9.0f;
    RPT16(RC_FINL64)
    __syncthreads();
    RPT16(RC_WL64)
    __syncthreads();
}

__global__ void __launch_bounds__(256, 1)
k_tail64(const float* __restrict__ pm2a, const int* __restrict__ i64p,
         const int* __restrict__ i64s, const float* __restrict__ wT,
         const float* __restrict__ wl, float* __restrict__ out){
    __shared__ float pm64[64][65];
    __shared__ float S64[64][65];
    int b = blockIdx.x, tid = threadIdx.x;
    int lane = tid & 63, w = tid >> 6;
    const float* PM = pm2a + (size_t)b * 256 * 64;
    const int* idp = i64p + (size_t)b * 64 * 8;
    for (int c = 0; c < 16; ++c){
        int col = w * 16 + c;
        const int* id = idp + col * 8;
        float v = -FLT_MAX;
        #pragma unroll
        for (int k = 0; k < 8; ++k)
            v = fmaxf(v, PM[(size_t)id[k] * 64 + lane]);
        pm64[col][lane] = v;
    }
    __syncthreads();
    const int* ids = i64s + (size_t)b * 64 * 8;
    for (int L = 0; L < 4; ++L)
        res_lds64g(pm64, S64, ids, wT + (size_t)(12 + L) * 4096,
                   wT + (size_t)(24 + L) * 4096, lane, w);
    if (tid < 64){
        float acc = 0.f;
        for (int d = 0; d < 64; ++d) acc += wl[d] * leaky(pm64[tid][d]);
        out[(size_t)b * 64 + tid] = acc;
    }
}

extern "C" void kernel_launch(void* const* d_in, const int* in_sizes, int n_in,
                              void* d_out, int out_size, void* d_ws, size_t ws_size,
                              hipStream_t stream){
    const float* xyz_in  = (const float*)d_in[0];
    const float* w0      = (const float*)d_in[1];
    const float* fn_wc   = (const float*)d_in[2];
    const float* fn_wg   = (const float*)d_in[3];
    const float* res_wc  = (const float*)d_in[4];
    const float* res_wg  = (const float*)d_in[5];
    const float* w_last  = (const float*)d_in[6];
    float* out = (float*)d_out;
    char* ws = (char*)d_ws;

    float* wT    = (float*)(ws + 0UL);
    float* dm4a  = (float*)(ws + 458752UL);
    float* dm4b  = (float*)(ws + 8847360UL);
    float* pm4a  = (float*)(ws + 17235968UL);
    float* pm4b  = (float*)(ws + 25624576UL);
    int*   idx4  = (int*)  (ws + 34013184UL);
    float* xyz1  = (float*)(ws + 35061760UL);
    float* xyz2  = (float*)(ws + 35160064UL);
    float* xyz3  = (float*)(ws + 35184640UL);
    int* i1024p  = (int*)(ws + 35190784UL);
    int* i1024s  = (int*)(ws + 35452928UL);
    int* i256p   = (int*)(ws + 35715072UL);
    int* i256s   = (int*)(ws + 35780608UL);
    int* i64p    = (int*)(ws + 35846144UL);
    int* i64s    = (int*)(ws + 35862528UL);
    float* fpssav = (float*)(ws + 35878912UL);   // 8 * 4160 floats
    float* dm1a = (float*)((char*)dm4b + 0UL);
    float* dm1b = (float*)((char*)dm4b + 2097152UL);
    float* dm2a = (float*)((char*)dm4b + 4194304UL);
    float* dm2b = (float*)((char*)dm4b + 4718592UL);
    float* pm1a = (float*)((char*)pm4b + 0UL);
    float* pm1b = (float*)((char*)pm4b + 2097152UL);
    float* pm2a = (float*)((char*)pm4b + 4194304UL);
    float* pm2b = (float*)((char*)pm4b + 4718592UL);

    // L1: fps16[1,512) || knn@4096 || transpose || conv0
    k_front<<<228, 256, 0, stream>>>(xyz_in, w0, fn_wc, fn_wg, res_wc, res_wg,
                                     wT, dm4a, pm4a, idx4, xyz1, fpssav);
    // L2: fps16[512,1024) || res4096#1
    k_frontb<<<256, 256, 0, stream>>>(xyz_in, wT, dm4a, pm4a, idx4,
                                      dm4b, pm4b, xyz1, fpssav);
    // L3: fps4 || res4096#2 || knn(1024,4096) || knn(1024,1024)
    k_mid1<<<584, 256, 0, stream>>>(xyz_in, xyz1, wT, dm4b, pm4b, idx4,
                                    dm4a, pm4a, i1024p, i1024s, xyz2);
    // L4: fps1 || pool1024 || knn(256,1024) || knn(256,256)
    k_mid2<<<152, 256, 0, stream>>>(xyz1, xyz2, pm4a, i1024p, dm1a, pm1a,
                                    i256p, i256s, xyz3);
    // L5: res1024#1 || knn(64,256) || knn(64,64)
    k_mid3<<<144, 256, 0, stream>>>(xyz2, xyz3, dm1a, pm1a, i1024s, wT,
                                    dm1b, pm1b, i64p, i64s);
    // L6-8: res@1024 #2-#4
    k_res_g<<<128, 256, 0, stream>>>(dm1b, pm1b, i1024s, wT + 5*4096, wT + 17*4096, dm1a, pm1a, 1024);
    k_res_g<<<128, 256, 0, stream>>>(dm1a, pm1a, i1024s, wT + 6*4096, wT + 18*4096, dm1b, pm1b, 1024);
    k_res_g<<<128, 256, 0, stream>>>(dm1b, pm1b, i1024s, wT + 7*4096, wT + 19*4096, dm1a, pm1a, 1024);
    // L9: pool@256
    k_pool_g<<<32, 256, 0, stream>>>(pm1a, i256p, dm2a, pm2a, 256, 1024);
    // L10-13: res@256 x4
    k_res_g<<<32, 256, 0, stream>>>(dm2a, pm2a, i256s, wT + 8*4096,  wT + 20*4096, dm2b, pm2b, 256);
    k_res_g<<<32, 256, 0, stream>>>(dm2b, pm2b, i256s, wT + 9*4096,  wT + 21*4096, dm2a, pm2a, 256);
    k_res_g<<<32, 256, 0, stream>>>(dm2a, pm2a, i256s, wT + 10*4096, wT + 22*4096, dm2b, pm2b, 256);
    k_res_g<<<32, 256, 0, stream>>>(dm2b, pm2b, i256s, wT + 11*4096, wT + 23*4096, dm2a, pm2a, 256);
    // L14: pool64 + res@64 x4 + final
    k_tail64<<<8, 256, 0, stream>>>(pm2a, i64p, i64s, wT, w_last, out);
}

// Round 19
// 1217.436 us; speedup vs baseline: 1.5770x; 1.5770x over previous
//
#include <hip/hip_runtime.h>
#include <hip/hip_bf16.h>
#include <float.h>

#define NEG_SLOPE 0.01f
typedef float v2f __attribute__((ext_vector_type(2)));
__device__ __forceinline__ float leaky(float x){ return x >= 0.0f ? x : NEG_SLOPE * x; }

#if !__has_builtin(__builtin_elementwise_fma)
#error "need __builtin_elementwise_fma"
#endif

#define RPT16(M) M(0) M(1) M(2) M(3) M(4) M(5) M(6) M(7) \
                 M(8) M(9) M(10) M(11) M(12) M(13) M(14) M(15)
#define RPT8(M) M(0) M(1) M(2) M(3) M(4) M(5) M(6) M(7)

// ================= kNN: 4-way ref-split, exact merge =================
// Block owns 64 queries (lane = query); wave w scans ref quarter. Partial
// top-8 per wave via the proven float-compare chain (ascending j => lowest
// idx wins ties). Merge: monotone u64 keys (mono(d)<<32 | idx) -> 32-key
// min-insert per query = exact global top-8 sorted by (d asc, idx asc),
// matching lax.top_k set AND order (downstream sums bit-identical).
#define KNN_INS(bdX, biX) { bool c = cd < bdX; float tf = bdX; int ti = biX; \
    bdX = c ? cd : bdX; biX = c ? ci : biX; cd = c ? tf : cd; ci = c ? ti : ci; }
#define KNN_PROC(r, jj) { \
    float dot = qx * r.x + qy * r.y + qz * r.z; \
    float dcur = qq + r.w - 2.0f * dot; \
    if (dcur < bd7){ \
        float cd = dcur; int ci = (jj); \
        KNN_INS(bd0, bi0); KNN_INS(bd1, bi1); KNN_INS(bd2, bi2); KNN_INS(bd3, bi3); \
        KNN_INS(bd4, bi4); KNN_INS(bd5, bi5); KNN_INS(bd6, bi6); KNN_INS(bd7, bi7); \
    } }

__device__ __forceinline__ unsigned mono(float d){
    unsigned u = __float_as_uint(d);
    return u ^ (unsigned)(((int)u >> 31) | 0x80000000);
}
#define MRG_INS(bX) { bool c_ = key < bX; unsigned long long t_ = bX; \
    bX = c_ ? key : bX; key = c_ ? t_ : key; }

__device__ void dev_knn4(int b, int m0, const float* q, int M,
                         const float* ref, int Nr, int* idx_out,
                         float4* sref, unsigned long long (*smrg)[32]){
    int tid = threadIdx.x, lane = tid & 63, w = tid >> 6;
    int m = m0 + lane;
    const float* Q = q + (size_t)b * 3 * M;
    const float* R = ref + (size_t)b * 3 * Nr;
    float qx = Q[m], qy = Q[M + m], qz = Q[2 * M + m];
    float qq = qx*qx + qy*qy + qz*qz;
    float bd0 = FLT_MAX, bd1 = FLT_MAX, bd2 = FLT_MAX, bd3 = FLT_MAX;
    float bd4 = FLT_MAX, bd5 = FLT_MAX, bd6 = FLT_MAX, bd7 = FLT_MAX;
    int bi0 = 0, bi1 = 0, bi2 = 0, bi3 = 0, bi4 = 0, bi5 = 0, bi6 = 0, bi7 = 0;
    for (int base = 0; base < Nr; base += 1024){
        int jmax = min(1024, Nr - base);
        for (int j = tid; j < jmax; j += 256){
            float rx = R[base + j], ry = R[Nr + base + j], rz = R[2 * Nr + base + j];
            sref[j] = make_float4(rx, ry, rz, rx*rx + ry*ry + rz*rz);
        }
        __syncthreads();
        int q4 = jmax >> 2;         // quarter per wave; always multiple of 4
        int j0 = w * q4;
        for (int j = j0; j < j0 + q4; j += 4){
            float4 r0 = sref[j+0]; float4 r1 = sref[j+1];
            float4 r2 = sref[j+2]; float4 r3 = sref[j+3];
            KNN_PROC(r0, base + j + 0)
            KNN_PROC(r1, base + j + 1)
            KNN_PROC(r2, base + j + 2)
            KNN_PROC(r3, base + j + 3)
        }
        __syncthreads();
    }
    unsigned long long* row = smrg[lane] + w * 8;
    row[0] = ((unsigned long long)mono(bd0) << 32) | (unsigned)bi0;
    row[1] = ((unsigned long long)mono(bd1) << 32) | (unsigned)bi1;
    row[2] = ((unsigned long long)mono(bd2) << 32) | (unsigned)bi2;
    row[3] = ((unsigned long long)mono(bd3) << 32) | (unsigned)bi3;
    row[4] = ((unsigned long long)mono(bd4) << 32) | (unsigned)bi4;
    row[5] = ((unsigned long long)mono(bd5) << 32) | (unsigned)bi5;
    row[6] = ((unsigned long long)mono(bd6) << 32) | (unsigned)bi6;
    row[7] = ((unsigned long long)mono(bd7) << 32) | (unsigned)bi7;
    __syncthreads();
    if (w == 0){
        unsigned long long k0=~0ull,k1=~0ull,k2=~0ull,k3=~0ull;
        unsigned long long k4=~0ull,k5=~0ull,k6=~0ull,k7=~0ull;
        #pragma unroll
        for (int s = 0; s < 32; ++s){
            unsigned long long key = smrg[lane][s];
            if (key < k7){
                MRG_INS(k0) MRG_INS(k1) MRG_INS(k2) MRG_INS(k3)
                MRG_INS(k4) MRG_INS(k5) MRG_INS(k6) MRG_INS(k7)
            }
        }
        int* o = idx_out + ((size_t)b * M + m) * 8;
        o[0] = (int)(unsigned)k0; o[1] = (int)(unsigned)k1;
        o[2] = (int)(unsigned)k2; o[3] = (int)(unsigned)k3;
        o[4] = (int)(unsigned)k4; o[5] = (int)(unsigned)k5;
        o[6] = (int)(unsigned)k6; o[7] = (int)(unsigned)k7;
    }
    __syncthreads();
}

// ================= res / pool / conv0 (verbatim r15-proven) =================
#define RC_DECL(i) float a##i = 0.f;
#define RC_FMA(i)  a##i = fmaf(wc[i], h, fmaf(wg[i], sv, a##i));
#define RC_FIN(i)  a##i = a##i * inv + Pr[(size_t)(i) * n];
#define RC_ST(i)   O[(size_t)(i) * n] = a##i;
#define RC_STPM(i) PO[i] = a##i;

__device__ void dev_res(int b, int j0, int n,
        const float* dmc, const float* pmc, const int* idx,
        const float* wc_, const float* wg_, float* dmo, float* pmo,
        float (*tile)[65]){
    int tid = threadIdx.x, lane = tid & 63, w = tid >> 6;
    const float* PM = pmc + (size_t)b * n * 64;
    const int* ID = idx + ((size_t)b * n + j0) * 8;
    for (int c = 0; c < 16; ++c){
        int jl = w * 16 + c;
        const int* id = ID + jl * 8;
        float v = 0.f;
        #pragma unroll
        for (int k = 0; k < 8; ++k)
            v += leaky(PM[(size_t)id[k] * 64 + lane]);
        tile[jl][lane] = v;
    }
    __syncthreads();
    int j = j0 + lane;
    const float* P = dmc + (size_t)b * 64 * n + j;
    const float* sc = &tile[lane][0];
    RPT16(RC_DECL)
    for (int d = 0; d < 64; ++d){
        float h  = leaky(P[(size_t)d * n]);
        float sv = sc[d];
        const float* wc = wc_ + d * 64 + w * 16;
        const float* wg = wg_ + d * 64 + w * 16;
        RPT16(RC_FMA)
    }
    const float inv = 1.0f / 9.0f;
    const float* Pr = P + (size_t)(w * 16) * n;
    RPT16(RC_FIN)
    float* O = dmo + ((size_t)b * 64 + w * 16) * n + j;
    RPT16(RC_ST)
    float* PO = pmo + ((size_t)b * n + j) * 64 + w * 16;
    RPT16(RC_STPM)
    __syncthreads();
}

__device__ void dev_pool(int b, int m0, int np, int nsrc,
        const float* pmc, const int* idx, float* dmo, float* pmo, float (*tile)[65]){
    int tid = threadIdx.x, lane = tid & 63, w = tid >> 6;
    const float* PM = pmc + (size_t)b * nsrc * 64;
    float* PMO = pmo + (size_t)b * np * 64;
    const int* ID = idx + ((size_t)b * np + m0) * 8;
    for (int c = 0; c < 16; ++c){
        int ml = w * 16 + c;
        const int* id = ID + ml * 8;
        float v = -FLT_MAX;
        #pragma unroll
        for (int k = 0; k < 8; ++k)
            v = fmaxf(v, PM[(size_t)id[k] * 64 + lane]);
        tile[ml][lane] = v;
        PMO[(size_t)(m0 + ml) * 64 + lane] = v;
    }
    __syncthreads();
    float* O = dmo + (size_t)b * 64 * np + m0;
    for (int c = 0; c < 16; ++c){
        int d = w * 16 + c;
        O[(size_t)d * np + lane] = tile[lane][d];
    }
    __syncthreads();
}

__device__ void dev_conv0(int t, const float* xyz, const float* w0,
                          float* dm, float* pm){
    int b = t >> 6;
    int lane = threadIdx.x & 63, w = threadIdx.x >> 6;
    int j = ((t & 63) << 6) + lane;
    const int n = 4096;
    const float* X = xyz + (size_t)b * 3 * n;
    float x = X[j], y = X[n + j], z = X[2 * n + j];
    float* PO = pm + ((size_t)b * n + j) * 64 + w * 16;
    #pragma unroll
    for (int c = 0; c < 16; ++c){
        int oo = w * 16 + c;
        float v = w0[oo*3] * x + w0[oo*3+1] * y + w0[oo*3+2] * z;
        dm[((size_t)b * 64 + oo) * n + j] = v;
        PO[c] = v;
    }
}

// ---- FPS primitives (r15-proven) ----
template<int CTRL>
__device__ __forceinline__ void dpp2(unsigned long long &bp){
    unsigned h = (unsigned)(bp >> 32), l = (unsigned)bp;
    unsigned th = (unsigned)__builtin_amdgcn_update_dpp(0, (int)h, CTRL, 0xF, 0xF, true);
    unsigned tl = (unsigned)__builtin_amdgcn_update_dpp(0, (int)l, CTRL, 0xF, 0xF, true);
    unsigned long long tp = ((unsigned long long)th << 32) | tl;
    bp = tp > bp ? tp : bp;
}
#define DPP_REDUCE2(bp) dpp2<0x111>(bp); dpp2<0x112>(bp); dpp2<0x114>(bp); \
    dpp2<0x118>(bp); dpp2<0x142>(bp); dpp2<0x143>(bp);

#define FPS_DECL(i) v2f px##i, py##i, pz##i, ds##i;
#define FPS_LOAD(i) { int g0 = tid + (2*(i))*T, g1 = g0 + T; \
    px##i = (v2f){X[g0], X[g1]}; py##i = (v2f){X[N+g0], X[N+g1]}; \
    pz##i = (v2f){X[2*N+g0], X[2*N+g1]}; ds##i = (v2f){1e10f, 1e10f}; }
#define FPS_PIN(i) asm volatile("" : "+v"(px##i), "+v"(py##i), "+v"(pz##i));
// dist >= 0 => float bit order == value order; ~gi larger => gi smaller, so
// u64 max == (dist >, tie: idx <) exactly.
#define FPS_UPD(i) { \
    v2f dx = px##i - l2x, dy = py##i - l2y, dz = pz##i - l2z; \
    v2f dd = __builtin_elementwise_fma(dz, dz, __builtin_elementwise_fma(dy, dy, dx*dx)); \
    float n0 = fminf(ds##i.x, dd.x), n1 = fminf(ds##i.y, dd.y); \
    ds##i = (v2f){n0, n1}; \
    unsigned long long c0 = ((unsigned long long)__float_as_uint(n0) << 32) | (unsigned)~(tid + (2*(i))*T); \
    unsigned long long c1 = ((unsigned long long)__float_as_uint(n1) << 32) | (unsigned)~(tid + (2*(i)+1)*T); \
    bp = c0 > bp ? c0 : bp; bp = c1 > bp ? c1 : bp; }

#define FPS_COMBINE(i) \
    int buf_ = (i) & 1; \
    if ((tid & 63) == 63) sred[buf_][tid >> 6] = bp; \
    __syncthreads(); \
    unsigned long long pp = sred[buf_][0]; \
    _Pragma("unroll") \
    for (int k_ = 1; k_ < 4; ++k_){ unsigned long long pk = sred[buf_][k_]; pp = pk > pp ? pk : pp; } \
    int i0 = (int)~(unsigned)pp; \
    float4 wn = sxyz[i0];

#define FPS_SAVE(i) { v2f t_ = ds##i; SV[tid * 16 + 2*(i)] = t_.x; SV[tid * 16 + 2*(i) + 1] = t_.y; }
#define FPS_REST(i) { ds##i = (v2f){SV[tid * 16 + 2*(i)], SV[tid * 16 + 2*(i) + 1]}; }

// ================= LAUNCH 1: fps16[1,512) || knn@4096(split) || transpose || conv0 =================
__global__ void __launch_bounds__(256, 1)
k_front(const float* __restrict__ xyz_in, const float* __restrict__ w0,
        const float* __restrict__ fn_wc, const float* __restrict__ fn_wg,
        const float* __restrict__ res_wc, const float* __restrict__ res_wg,
        float* __restrict__ wT, float* __restrict__ dm4a, float* __restrict__ pm4a,
        int* __restrict__ idx4, float* __restrict__ xyz1, float* __restrict__ fpssav){
    __shared__ __align__(16) char LB[66560];
    __shared__ unsigned long long sred[2][4];
    int bid = blockIdx.x, tid = threadIdx.x;
    if (bid < 8){
        float4* sxyz = (float4*)LB;
        constexpr int N = 4096, T = 256;
        const float* X = xyz_in + (size_t)bid * 3 * N;
        RPT8(FPS_DECL) RPT8(FPS_LOAD) RPT8(FPS_PIN)
        for (int t = tid; t < N; t += T)
            sxyz[t] = make_float4(X[t], X[N+t], X[2*N+t], 0.f);
        float* NX_ = xyz1 + (size_t)bid * 3 * 1024;
        if (tid == 0){ NX_[0] = X[0]; NX_[1024] = X[N]; NX_[2048] = X[2*N]; }
        v2f l2x = (v2f){X[0], X[0]}, l2y = (v2f){X[N], X[N]}, l2z = (v2f){X[2*N], X[2*N]};
        __syncthreads();
        for (int i = 1; i < 512; ++i){
            unsigned long long bp = 0;
            RPT8(FPS_UPD)
            DPP_REDUCE2(bp)
            FPS_COMBINE(i)
            l2x = (v2f){wn.x, wn.x}; l2y = (v2f){wn.y, wn.y}; l2z = (v2f){wn.z, wn.z};
            if (tid == 0){ NX_[i] = wn.x; NX_[1024 + i] = wn.y; NX_[2048 + i] = wn.z; }
        }
        float* SV = fpssav + (size_t)bid * 4160;
        RPT8(FPS_SAVE)
        if (tid == 0){ SV[4096] = l2x.x; SV[4097] = l2y.x; SV[4098] = l2z.x; }
    } else if (bid < 520){
        int u = bid - 8;
        dev_knn4(u >> 6, (u & 63) << 6, xyz_in, 4096, xyz_in, 4096, idx4,
                 (float4*)LB, (unsigned long long (*)[32])(LB + 16384));
    } else if (bid < 548){
        int m = bid - 520;
        const float* s;
        if (m < 2) s = fn_wc + (size_t)m * 4096;
        else if (m < 4) s = fn_wg + (size_t)(m - 2) * 4096;
        else if (m < 16) s = res_wc + (size_t)(m - 4) * 4096;
        else s = res_wg + (size_t)(m - 16) * 4096;
        float* o = wT + (size_t)m * 4096;
        for (int t = tid; t < 4096; t += 256){
            int oo = t >> 6, dd = t & 63;
            o[dd * 64 + oo] = s[t];
        }
    } else {
        for (int t = bid - 548; t < 512; t += 64)
            dev_conv0(t, xyz_in, w0, dm4a, pm4a);
    }
}

// ================= LAUNCH 2: fps16[512,1024) || res4096#1 =================
__global__ void __launch_bounds__(256, 1)
k_frontb(const float* __restrict__ xyz_in, const float* __restrict__ wT,
         const float* __restrict__ dm4a, const float* __restrict__ pm4a,
         const int* __restrict__ idx4,
         float* __restrict__ dm4b, float* __restrict__ pm4b,
         float* __restrict__ xyz1, const float* __restrict__ fpssav){
    __shared__ __align__(16) char LB[66560];
    __shared__ unsigned long long sred[2][4];
    int bid = blockIdx.x, tid = threadIdx.x;
    if (bid < 8){
        float4* sxyz = (float4*)LB;
        constexpr int N = 4096, T = 256;
        const float* X = xyz_in + (size_t)bid * 3 * N;
        const float* SV = fpssav + (size_t)bid * 4160;
        RPT8(FPS_DECL) RPT8(FPS_LOAD) RPT8(FPS_PIN)
        RPT8(FPS_REST)
        for (int t = tid; t < N; t += T)
            sxyz[t] = make_float4(X[t], X[N+t], X[2*N+t], 0.f);
        float lx0 = SV[4096], ly0 = SV[4097], lz0 = SV[4098];
        v2f l2x = (v2f){lx0, lx0}, l2y = (v2f){ly0, ly0}, l2z = (v2f){lz0, lz0};
        float* NX_ = xyz1 + (size_t)bid * 3 * 1024;
        __syncthreads();
        for (int i = 512; i < 1024; ++i){
            unsigned long long bp = 0;
            RPT8(FPS_UPD)
            DPP_REDUCE2(bp)
            FPS_COMBINE(i)
            l2x = (v2f){wn.x, wn.x}; l2y = (v2f){wn.y, wn.y}; l2z = (v2f){wn.z, wn.z};
            if (tid == 0){ NX_[i] = wn.x; NX_[1024 + i] = wn.y; NX_[2048 + i] = wn.z; }
        }
    } else {
        for (int t = bid - 8; t < 512; t += 248)
            dev_res(t >> 6, (t & 63) << 6, 4096, dm4a, pm4a, idx4,
                    wT + 0 * 4096, wT + 2 * 4096, dm4b, pm4b, (float (*)[65])LB);
    }
}

// ================= LAUNCH 3: fps4 || res4096#2 || knn(1024,4096) || knn(1024,1024) =================
__global__ void __launch_bounds__(256, 1)
k_mid1(const float* __restrict__ xyz_in, const float* __restrict__ xyz1,
       const float* __restrict__ wT,
       const float* __restrict__ dm4b, const float* __restrict__ pm4b,
       const int* __restrict__ idx4,
       float* __restrict__ dm4a, float* __restrict__ pm4a,
       int* __restrict__ i1024p, int* __restrict__ i1024s,
       float* __restrict__ xyz2){
    __shared__ __align__(16) char LB[32768];
    __shared__ unsigned long long sred[2][4];
    int bid = blockIdx.x, tid = threadIdx.x;
    if (bid < 8){
        float4* sxyz = (float4*)LB;
        constexpr int N = 1024, T = 256;
        const float* X = xyz1 + (size_t)bid * 3 * N;
        FPS_DECL(0) FPS_DECL(1)
        FPS_LOAD(0) FPS_LOAD(1) FPS_PIN(0) FPS_PIN(1)
        for (int t = tid; t < N; t += T)
            sxyz[t] = make_float4(X[t], X[N+t], X[2*N+t], 0.f);
        float* NX_ = xyz2 + (size_t)bid * 3 * 256;
        if (tid == 0){ NX_[0] = X[0]; NX_[256] = X[N]; NX_[512] = X[2*N]; }
        v2f l2x = (v2f){X[0], X[0]}, l2y = (v2f){X[N], X[N]}, l2z = (v2f){X[2*N], X[2*N]};
        __syncthreads();
        for (int i = 1; i < 256; ++i){
            unsigned long long bp = 0;
            FPS_UPD(0) FPS_UPD(1)
            DPP_REDUCE2(bp)
            FPS_COMBINE(i)
            l2x = (v2f){wn.x, wn.x}; l2y = (v2f){wn.y, wn.y}; l2z = (v2f){wn.z, wn.z};
            if (tid == 0){ NX_[i] = wn.x; NX_[256 + i] = wn.y; NX_[512 + i] = wn.z; }
        }
    } else if (bid < 520){
        int t = bid - 8;
        dev_res(t >> 6, (t & 63) << 6, 4096, dm4b, pm4b, idx4,
                wT + 1 * 4096, wT + 3 * 4096, dm4a, pm4a, (float (*)[65])LB);
    } else if (bid < 648){
        int u = bid - 520;
        dev_knn4(u >> 4, (u & 15) << 6, xyz1, 1024, xyz_in, 4096, i1024p,
                 (float4*)LB, (unsigned long long (*)[32])(LB + 16384));
    } else {
        int u = bid - 648;
        dev_knn4(u >> 4, (u & 15) << 6, xyz1, 1024, xyz1, 1024, i1024s,
                 (float4*)LB, (unsigned long long (*)[32])(LB + 16384));
    }
}

// ================= LAUNCH 4: fps1 || pool1024 || knn(256,1024) || knn(256,256) =================
__global__ void __launch_bounds__(256, 1)
k_mid2(const float* __restrict__ xyz1, const float* __restrict__ xyz2,
       const float* __restrict__ pm4a, const int* __restrict__ i1024p,
       float* __restrict__ dm1a, float* __restrict__ pm1a,
       int* __restrict__ i256p, int* __restrict__ i256s,
       float* __restrict__ xyz3){
    __shared__ __align__(16) char LB[32768];
    __shared__ unsigned long long sred[2][4];
    int bid = blockIdx.x, tid = threadIdx.x;
    if (bid < 8){
        float4* sxyz = (float4*)LB;
        const float* X2 = xyz2 + (size_t)bid * 3 * 256;
        for (int t = tid; t < 256; t += 256)
            sxyz[t] = make_float4(X2[t], X2[256 + t], X2[512 + t], 0.f);
        float s1x = X2[tid], s1y = X2[256 + tid], s1z = X2[512 + tid], s1d = 1e10f;
        asm volatile("" : "+v"(s1x), "+v"(s1y), "+v"(s1z));
        float* NX_ = xyz3 + (size_t)bid * 3 * 64;
        if (tid == 0){ NX_[0] = X2[0]; NX_[64] = X2[256]; NX_[128] = X2[512]; }
        float lx = X2[0], ly = X2[256], lz = X2[512];
        __syncthreads();
        for (int i = 1; i < 64; ++i){
            float dx = s1x - lx, dy = s1y - ly, dz = s1z - lz;
            float dd = fmaf(dz, dz, fmaf(dy, dy, dx*dx));
            float nd = fminf(s1d, dd); s1d = nd;
            unsigned long long bp = ((unsigned long long)__float_as_uint(nd) << 32) | (unsigned)~tid;
            DPP_REDUCE2(bp)
            FPS_COMBINE(i)
            lx = wn.x; ly = wn.y; lz = wn.z;
            if (tid == 0){ NX_[i] = wn.x; NX_[64 + i] = wn.y; NX_[128 + i] = wn.z; }
        }
    } else if (bid < 136){
        int u = bid - 8;
        dev_pool(u >> 4, (u & 15) << 6, 1024, 4096, pm4a, i1024p,
                 dm1a, pm1a, (float (*)[65])LB);
    } else if (bid < 168){
        int u = bid - 136;
        dev_knn4(u >> 2, (u & 3) << 6, xyz2, 256, xyz1, 1024, i256p,
                 (float4*)LB, (unsigned long long (*)[32])(LB + 16384));
    } else {
        int u = bid - 168;
        dev_knn4(u >> 2, (u & 3) << 6, xyz2, 256, xyz2, 256, i256s,
                 (float4*)LB, (unsigned long long (*)[32])(LB + 16384));
    }
}

// ================= LAUNCH 5: res1024#1 || knn(64,256) || knn(64,64) =================
__global__ void __launch_bounds__(256, 1)
k_mid3(const float* __restrict__ xyz2, const float* __restrict__ xyz3,
       const float* __restrict__ dm1a, const float* __restrict__ pm1a,
       const int* __restrict__ i1024s, const float* __restrict__ wT,
       float* __restrict__ dm1b, float* __restrict__ pm1b,
       int* __restrict__ i64p, int* __restrict__ i64s){
    __shared__ __align__(16) char LB[32768];
    int bid = blockIdx.x;
    if (bid < 128){
        dev_res(bid >> 4, (bid & 15) << 6, 1024, dm1a, pm1a, i1024s,
                wT + 4 * 4096, wT + 16 * 4096, dm1b, pm1b, (float (*)[65])LB);
    } else if (bid < 136){
        dev_knn4(bid - 128, 0, xyz3, 64, xyz2, 256, i64p,
                 (float4*)LB, (unsigned long long (*)[32])(LB + 16384));
    } else {
        dev_knn4(bid - 136, 0, xyz3, 64, xyz3, 64, i64s,
                 (float4*)LB, (unsigned long long (*)[32])(LB + 16384));
    }
}

// ================= generic res / pool launches =================
__global__ void __launch_bounds__(256, 1)
k_res_g(const float* __restrict__ dmc, const float* __restrict__ pmc,
        const int* __restrict__ idx, const float* __restrict__ wc_,
        const float* __restrict__ wg_, float* __restrict__ dmo,
        float* __restrict__ pmo, int n){
    __shared__ float tile[64][65];
    int tiles = n >> 6;
    int b = blockIdx.x / tiles, j0 = (blockIdx.x % tiles) << 6;
    dev_res(b, j0, n, dmc, pmc, idx, wc_, wg_, dmo, pmo, tile);
}

__global__ void __launch_bounds__(256, 1)
k_pool_g(const float* __restrict__ pmc, const int* __restrict__ idx,
         float* __restrict__ dmo, float* __restrict__ pmo, int np, int nsrc){
    __shared__ float tile[64][65];
    int tiles = np >> 6;
    int b = blockIdx.x / tiles, m0 = (blockIdx.x % tiles) << 6;
    dev_pool(b, m0, np, nsrc, pmc, idx, dmo, pmo, tile);
}

// ================= tail: pool64 + 4x res64 (in-LDS) + final =================
#define RC_FINL64(i) a##i = a##i * inv + pmX[lane][w16 + (i)];
#define RC_WL64(i)   pmX[lane][w16 + (i)] = a##i;

__device__ __forceinline__ void res_lds64g(float (*pmX)[65], float (*S)[65],
        const int* idg, const float* __restrict__ wcT, const float* __restrict__ wgT,
        int lane, int w){
    for (int c = 0; c < 16; ++c){
        int col = w * 16 + c;
        const int* id = idg + col * 8;
        float v = 0.f;
        #pragma unroll
        for (int k = 0; k < 8; ++k) v += leaky(pmX[id[k]][lane]);
        S[col][lane] = v;
    }
    __syncthreads();
    int w16 = w * 16;
    RPT16(RC_DECL)
    #pragma unroll 2
    for (int d = 0; d < 64; ++d){
        float h  = leaky(pmX[lane][d]);
        float sv = S[lane][d];
        const float* wc = wcT + d * 64 + w16;
        const float* wg = wgT + d * 64 + w16;
        RPT16(RC_FMA)
    }
    const float inv = 1.0f / 9.0f;
    RPT16(RC_FINL64)
    __syncthreads();
    RPT16(RC_WL64)
    __syncthreads();
}

__global__ void __launch_bounds__(256, 1)
k_tail64(const float* __restrict__ pm2a, const int* __restrict__ i64p,
         const int* __restrict__ i64s, const float* __restrict__ wT,
         const float* __restrict__ wl, float* __restrict__ out){
    __shared__ float pm64[64][65];
    __shared__ float S64[64][65];
    int b = blockIdx.x, tid = threadIdx.x;
    int lane = tid & 63, w = tid >> 6;
    const float* PM = pm2a + (size_t)b * 256 * 64;
    const int* idp = i64p + (size_t)b * 64 * 8;
    for (int c = 0; c < 16; ++c){
        int col = w * 16 + c;
        const int* id = idp + col * 8;
        float v = -FLT_MAX;
        #pragma unroll
        for (int k = 0; k < 8; ++k)
            v = fmaxf(v, PM[(size_t)id[k] * 64 + lane]);
        pm64[col][lane] = v;
    }
    __syncthreads();
    const int* ids = i64s + (size_t)b * 64 * 8;
    for (int L = 0; L < 4; ++L)
        res_lds64g(pm64, S64, ids, wT + (size_t)(12 + L) * 4096,
                   wT + (size_t)(24 + L) * 4096, lane, w);
    if (tid < 64){
        float acc = 0.f;
        for (int d = 0; d < 64; ++d) acc += wl[d] * leaky(pm64[tid][d]);
        out[(size_t)b * 64 + tid] = acc;
    }
}

extern "C" void kernel_launch(void* const* d_in, const int* in_sizes, int n_in,
                              void* d_out, int out_size, void* d_ws, size_t ws_size,
                              hipStream_t stream){
    const float* xyz_in  = (const float*)d_in[0];
    const float* w0      = (const float*)d_in[1];
    const float* fn_wc   = (const float*)d_in[2];
    const float* fn_wg   = (const float*)d_in[3];
    const float* res_wc  = (const float*)d_in[4];
    const float* res_wg  = (const float*)d_in[5];
    const float* w_last  = (const float*)d_in[6];
    float* out = (float*)d_out;
    char* ws = (char*)d_ws;

    float* wT    = (float*)(ws + 0UL);
    float* dm4a  = (float*)(ws + 458752UL);
    float* dm4b  = (float*)(ws + 8847360UL);
    float* pm4a  = (float*)(ws + 17235968UL);
    float* pm4b  = (float*)(ws + 25624576UL);
    int*   idx4  = (int*)  (ws + 34013184UL);
    float* xyz1  = (float*)(ws + 35061760UL);
    float* xyz2  = (float*)(ws + 35160064UL);
    float* xyz3  = (float*)(ws + 35184640UL);
    int* i1024p  = (int*)(ws + 35190784UL);
    int* i1024s  = (int*)(ws + 35452928UL);
    int* i256p   = (int*)(ws + 35715072UL);
    int* i256s   = (int*)(ws + 35780608UL);
    int* i64p    = (int*)(ws + 35846144UL);
    int* i64s    = (int*)(ws + 35862528UL);
    float* fpssav = (float*)(ws + 35878912UL);
    float* dm1a = (float*)((char*)dm4b + 0UL);
    float* dm1b = (float*)((char*)dm4b + 2097152UL);
    float* dm2a = (float*)((char*)dm4b + 4194304UL);
    float* dm2b = (float*)((char*)dm4b + 4718592UL);
    float* pm1a = (float*)((char*)pm4b + 0UL);
    float* pm1b = (float*)((char*)pm4b + 2097152UL);
    float* pm2a = (float*)((char*)pm4b + 4194304UL);
    float* pm2b = (float*)((char*)pm4b + 4718592UL);

    // L1: fps16[1,512) || knn@4096(split) || transpose || conv0
    k_front<<<612, 256, 0, stream>>>(xyz_in, w0, fn_wc, fn_wg, res_wc, res_wg,
                                     wT, dm4a, pm4a, idx4, xyz1, fpssav);
    // L2: fps16[512,1024) || res4096#1
    k_frontb<<<256, 256, 0, stream>>>(xyz_in, wT, dm4a, pm4a, idx4,
                                      dm4b, pm4b, xyz1, fpssav);
    // L3: fps4 || res4096#2 || knn(1024,4096) || knn(1024,1024)
    k_mid1<<<776, 256, 0, stream>>>(xyz_in, xyz1, wT, dm4b, pm4b, idx4,
                                    dm4a, pm4a, i1024p, i1024s, xyz2);
    // L4: fps1 || pool1024 || knn(256,1024) || knn(256,256)
    k_mid2<<<200, 256, 0, stream>>>(xyz1, xyz2, pm4a, i1024p, dm1a, pm1a,
                                    i256p, i256s, xyz3);
    // L5: res1024#1 || knn(64,256) || knn(64,64)
    k_mid3<<<144, 256, 0, stream>>>(xyz2, xyz3, dm1a, pm1a, i1024s, wT,
                                    dm1b, pm1b, i64p, i64s);
    // L6-8: res@1024 #2-#4
    k_res_g<<<128, 256, 0, stream>>>(dm1b, pm1b, i1024s, wT + 5*4096, wT + 17*4096, dm1a, pm1a, 1024);
    k_res_g<<<128, 256, 0, stream>>>(dm1a, pm1a, i1024s, wT + 6*4096, wT + 18*4096, dm1b, pm1b, 1024);
    k_res_g<<<128, 256, 0, stream>>>(dm1b, pm1b, i1024s, wT + 7*4096, wT + 19*4096, dm1a, pm1a, 1024);
    // L9: pool@256
    k_pool_g<<<32, 256, 0, stream>>>(pm1a, i256p, dm2a, pm2a, 256, 1024);
    // L10-13: res@256 x4
    k_res_g<<<32, 256, 0, stream>>>(dm2a, pm2a, i256s, wT + 8*4096,  wT + 20*4096, dm2b, pm2b, 256);
    k_res_g<<<32, 256, 0, stream>>>(dm2b, pm2b, i256s, wT + 9*4096,  wT + 21*4096, dm2a, pm2a, 256);
    k_res_g<<<32, 256, 0, stream>>>(dm2a, pm2a, i256s, wT + 10*4096, wT + 22*4096, dm2b, pm2b, 256);
    k_res_g<<<32, 256, 0, stream>>>(dm2b, pm2b, i256s, wT + 11*4096, wT + 23*4096, dm2a, pm2a, 256);
    // L14: pool64 + res@64 x4 + final
    k_tail64<<<8, 256, 0, stream>>>(pm2a, i64p, i64s, wT, w_last, out);
}

// Round 20
// 1209.530 us; speedup vs baseline: 1.5873x; 1.0065x over previous
//
#include <hip/hip_runtime.h>
#include <hip/hip_bf16.h>
#include <float.h>

#define NEG_SLOPE 0.01f
typedef float v2f __attribute__((ext_vector_type(2)));
__device__ __forceinline__ float leaky(float x){ return x >= 0.0f ? x : NEG_SLOPE * x; }

#if !__has_builtin(__builtin_elementwise_fma)
#error "need __builtin_elementwise_fma"
#endif

#define RPT16(M) M(0) M(1) M(2) M(3) M(4) M(5) M(6) M(7) \
                 M(8) M(9) M(10) M(11) M(12) M(13) M(14) M(15)
#define RPT8(M) M(0) M(1) M(2) M(3) M(4) M(5) M(6) M(7)

// ================= kNN: 4-way ref-split, exact merge =================
// r20: smrg padded [64][32] -> [64][33]. u64 row stride 256B put every lane
// on the same bank pair (32-way conflict, 2.0M SQ_LDS_BANK_CONFLICT in r19).
// Stride 264B spreads lanes across 16 banks (worst 4-way = 1.58x, near-free).
#define KNN_INS(bdX, biX) { bool c = cd < bdX; float tf = bdX; int ti = biX; \
    bdX = c ? cd : bdX; biX = c ? ci : biX; cd = c ? tf : cd; ci = c ? ti : ci; }
#define KNN_PROC(r, jj) { \
    float dot = qx * r.x + qy * r.y + qz * r.z; \
    float dcur = qq + r.w - 2.0f * dot; \
    if (dcur < bd7){ \
        float cd = dcur; int ci = (jj); \
        KNN_INS(bd0, bi0); KNN_INS(bd1, bi1); KNN_INS(bd2, bi2); KNN_INS(bd3, bi3); \
        KNN_INS(bd4, bi4); KNN_INS(bd5, bi5); KNN_INS(bd6, bi6); KNN_INS(bd7, bi7); \
    } }

__device__ __forceinline__ unsigned mono(float d){
    unsigned u = __float_as_uint(d);
    return u ^ (unsigned)(((int)u >> 31) | 0x80000000);
}
#define MRG_INS(bX) { bool c_ = key < bX; unsigned long long t_ = bX; \
    bX = c_ ? key : bX; key = c_ ? t_ : key; }

__device__ void dev_knn4(int b, int m0, const float* q, int M,
                         const float* ref, int Nr, int* idx_out,
                         float4* sref, unsigned long long (*smrg)[33]){
    int tid = threadIdx.x, lane = tid & 63, w = tid >> 6;
    int m = m0 + lane;
    const float* Q = q + (size_t)b * 3 * M;
    const float* R = ref + (size_t)b * 3 * Nr;
    float qx = Q[m], qy = Q[M + m], qz = Q[2 * M + m];
    float qq = qx*qx + qy*qy + qz*qz;
    float bd0 = FLT_MAX, bd1 = FLT_MAX, bd2 = FLT_MAX, bd3 = FLT_MAX;
    float bd4 = FLT_MAX, bd5 = FLT_MAX, bd6 = FLT_MAX, bd7 = FLT_MAX;
    int bi0 = 0, bi1 = 0, bi2 = 0, bi3 = 0, bi4 = 0, bi5 = 0, bi6 = 0, bi7 = 0;
    for (int base = 0; base < Nr; base += 1024){
        int jmax = min(1024, Nr - base);
        for (int j = tid; j < jmax; j += 256){
            float rx = R[base + j], ry = R[Nr + base + j], rz = R[2 * Nr + base + j];
            sref[j] = make_float4(rx, ry, rz, rx*rx + ry*ry + rz*rz);
        }
        __syncthreads();
        int q4 = jmax >> 2;         // quarter per wave; always multiple of 4
        int j0 = w * q4;
        for (int j = j0; j < j0 + q4; j += 4){
            float4 r0 = sref[j+0]; float4 r1 = sref[j+1];
            float4 r2 = sref[j+2]; float4 r3 = sref[j+3];
            KNN_PROC(r0, base + j + 0)
            KNN_PROC(r1, base + j + 1)
            KNN_PROC(r2, base + j + 2)
            KNN_PROC(r3, base + j + 3)
        }
        __syncthreads();
    }
    unsigned long long* row = smrg[lane] + w * 8;
    row[0] = ((unsigned long long)mono(bd0) << 32) | (unsigned)bi0;
    row[1] = ((unsigned long long)mono(bd1) << 32) | (unsigned)bi1;
    row[2] = ((unsigned long long)mono(bd2) << 32) | (unsigned)bi2;
    row[3] = ((unsigned long long)mono(bd3) << 32) | (unsigned)bi3;
    row[4] = ((unsigned long long)mono(bd4) << 32) | (unsigned)bi4;
    row[5] = ((unsigned long long)mono(bd5) << 32) | (unsigned)bi5;
    row[6] = ((unsigned long long)mono(bd6) << 32) | (unsigned)bi6;
    row[7] = ((unsigned long long)mono(bd7) << 32) | (unsigned)bi7;
    __syncthreads();
    if (w == 0){
        unsigned long long k0=~0ull,k1=~0ull,k2=~0ull,k3=~0ull;
        unsigned long long k4=~0ull,k5=~0ull,k6=~0ull,k7=~0ull;
        #pragma unroll
        for (int s = 0; s < 32; ++s){
            unsigned long long key = smrg[lane][s];
            if (key < k7){
                MRG_INS(k0) MRG_INS(k1) MRG_INS(k2) MRG_INS(k3)
                MRG_INS(k4) MRG_INS(k5) MRG_INS(k6) MRG_INS(k7)
            }
        }
        int* o = idx_out + ((size_t)b * M + m) * 8;
        o[0] = (int)(unsigned)k0; o[1] = (int)(unsigned)k1;
        o[2] = (int)(unsigned)k2; o[3] = (int)(unsigned)k3;
        o[4] = (int)(unsigned)k4; o[5] = (int)(unsigned)k5;
        o[6] = (int)(unsigned)k6; o[7] = (int)(unsigned)k7;
    }
    __syncthreads();
}

// ================= res / pool / conv0 (verbatim r15-proven) =================
#define RC_DECL(i) float a##i = 0.f;
#define RC_FMA(i)  a##i = fmaf(wc[i], h, fmaf(wg[i], sv, a##i));
#define RC_FIN(i)  a##i = a##i * inv + Pr[(size_t)(i) * n];
#define RC_ST(i)   O[(size_t)(i) * n] = a##i;
#define RC_STPM(i) PO[i] = a##i;

__device__ void dev_res(int b, int j0, int n,
        const float* dmc, const float* pmc, const int* idx,
        const float* wc_, const float* wg_, float* dmo, float* pmo,
        float (*tile)[65]){
    int tid = threadIdx.x, lane = tid & 63, w = tid >> 6;
    const float* PM = pmc + (size_t)b * n * 64;
    const int* ID = idx + ((size_t)b * n + j0) * 8;
    for (int c = 0; c < 16; ++c){
        int jl = w * 16 + c;
        const int* id = ID + jl * 8;
        float v = 0.f;
        #pragma unroll
        for (int k = 0; k < 8; ++k)
            v += leaky(PM[(size_t)id[k] * 64 + lane]);
        tile[jl][lane] = v;
    }
    __syncthreads();
    int j = j0 + lane;
    const float* P = dmc + (size_t)b * 64 * n + j;
    const float* sc = &tile[lane][0];
    RPT16(RC_DECL)
    for (int d = 0; d < 64; ++d){
        float h  = leaky(P[(size_t)d * n]);
        float sv = sc[d];
        const float* wc = wc_ + d * 64 + w * 16;
        const float* wg = wg_ + d * 64 + w * 16;
        RPT16(RC_FMA)
    }
    const float inv = 1.0f / 9.0f;
    const float* Pr = P + (size_t)(w * 16) * n;
    RPT16(RC_FIN)
    float* O = dmo + ((size_t)b * 64 + w * 16) * n + j;
    RPT16(RC_ST)
    float* PO = pmo + ((size_t)b * n + j) * 64 + w * 16;
    RPT16(RC_STPM)
    __syncthreads();
}

__device__ void dev_pool(int b, int m0, int np, int nsrc,
        const float* pmc, const int* idx, float* dmo, float* pmo, float (*tile)[65]){
    int tid = threadIdx.x, lane = tid & 63, w = tid >> 6;
    const float* PM = pmc + (size_t)b * nsrc * 64;
    float* PMO = pmo + (size_t)b * np * 64;
    const int* ID = idx + ((size_t)b * np + m0) * 8;
    for (int c = 0; c < 16; ++c){
        int ml = w * 16 + c;
        const int* id = ID + ml * 8;
        float v = -FLT_MAX;
        #pragma unroll
        for (int k = 0; k < 8; ++k)
            v = fmaxf(v, PM[(size_t)id[k] * 64 + lane]);
        tile[ml][lane] = v;
        PMO[(size_t)(m0 + ml) * 64 + lane] = v;
    }
    __syncthreads();
    float* O = dmo + (size_t)b * 64 * np + m0;
    for (int c = 0; c < 16; ++c){
        int d = w * 16 + c;
        O[(size_t)d * np + lane] = tile[lane][d];
    }
    __syncthreads();
}

__device__ void dev_conv0(int t, const float* xyz, const float* w0,
                          float* dm, float* pm){
    int b = t >> 6;
    int lane = threadIdx.x & 63, w = threadIdx.x >> 6;
    int j = ((t & 63) << 6) + lane;
    const int n = 4096;
    const float* X = xyz + (size_t)b * 3 * n;
    float x = X[j], y = X[n + j], z = X[2 * n + j];
    float* PO = pm + ((size_t)b * n + j) * 64 + w * 16;
    #pragma unroll
    for (int c = 0; c < 16; ++c){
        int oo = w * 16 + c;
        float v = w0[oo*3] * x + w0[oo*3+1] * y + w0[oo*3+2] * z;
        dm[((size_t)b * 64 + oo) * n + j] = v;
        PO[c] = v;
    }
}

// ---- FPS primitives (r15-proven) ----
template<int CTRL>
__device__ __forceinline__ void dpp2(unsigned long long &bp){
    unsigned h = (unsigned)(bp >> 32), l = (unsigned)bp;
    unsigned th = (unsigned)__builtin_amdgcn_update_dpp(0, (int)h, CTRL, 0xF, 0xF, true);
    unsigned tl = (unsigned)__builtin_amdgcn_update_dpp(0, (int)l, CTRL, 0xF, 0xF, true);
    unsigned long long tp = ((unsigned long long)th << 32) | tl;
    bp = tp > bp ? tp : bp;
}
#define DPP_REDUCE2(bp) dpp2<0x111>(bp); dpp2<0x112>(bp); dpp2<0x114>(bp); \
    dpp2<0x118>(bp); dpp2<0x142>(bp); dpp2<0x143>(bp);

#define FPS_DECL(i) v2f px##i, py##i, pz##i, ds##i;
#define FPS_LOAD(i) { int g0 = tid + (2*(i))*T, g1 = g0 + T; \
    px##i = (v2f){X[g0], X[g1]}; py##i = (v2f){X[N+g0], X[N+g1]}; \
    pz##i = (v2f){X[2*N+g0], X[2*N+g1]}; ds##i = (v2f){1e10f, 1e10f}; }
#define FPS_PIN(i) asm volatile("" : "+v"(px##i), "+v"(py##i), "+v"(pz##i));
// dist >= 0 => float bit order == value order; ~gi larger => gi smaller, so
// u64 max == (dist >, tie: idx <) exactly.
#define FPS_UPD(i) { \
    v2f dx = px##i - l2x, dy = py##i - l2y, dz = pz##i - l2z; \
    v2f dd = __builtin_elementwise_fma(dz, dz, __builtin_elementwise_fma(dy, dy, dx*dx)); \
    float n0 = fminf(ds##i.x, dd.x), n1 = fminf(ds##i.y, dd.y); \
    ds##i = (v2f){n0, n1}; \
    unsigned long long c0 = ((unsigned long long)__float_as_uint(n0) << 32) | (unsigned)~(tid + (2*(i))*T); \
    unsigned long long c1 = ((unsigned long long)__float_as_uint(n1) << 32) | (unsigned)~(tid + (2*(i)+1)*T); \
    bp = c0 > bp ? c0 : bp; bp = c1 > bp ? c1 : bp; }

#define FPS_COMBINE(i) \
    int buf_ = (i) & 1; \
    if ((tid & 63) == 63) sred[buf_][tid >> 6] = bp; \
    __syncthreads(); \
    unsigned long long pp = sred[buf_][0]; \
    _Pragma("unroll") \
    for (int k_ = 1; k_ < 4; ++k_){ unsigned long long pk = sred[buf_][k_]; pp = pk > pp ? pk : pp; } \
    int i0 = (int)~(unsigned)pp; \
    float4 wn = sxyz[i0];

#define FPS_SAVE(i) { v2f t_ = ds##i; SV[tid * 16 + 2*(i)] = t_.x; SV[tid * 16 + 2*(i) + 1] = t_.y; }
#define FPS_REST(i) { ds##i = (v2f){SV[tid * 16 + 2*(i)], SV[tid * 16 + 2*(i) + 1]}; }

// ================= LAUNCH 1: fps16[1,512) || knn@4096(split) || transpose || conv0 =================
__global__ void __launch_bounds__(256, 1)
k_front(const float* __restrict__ xyz_in, const float* __restrict__ w0,
        const float* __restrict__ fn_wc, const float* __restrict__ fn_wg,
        const float* __restrict__ res_wc, const float* __restrict__ res_wg,
        float* __restrict__ wT, float* __restrict__ dm4a, float* __restrict__ pm4a,
        int* __restrict__ idx4, float* __restrict__ xyz1, float* __restrict__ fpssav){
    __shared__ __align__(16) char LB[66560];
    __shared__ unsigned long long sred[2][4];
    int bid = blockIdx.x, tid = threadIdx.x;
    if (bid < 8){
        float4* sxyz = (float4*)LB;
        constexpr int N = 4096, T = 256;
        const float* X = xyz_in + (size_t)bid * 3 * N;
        RPT8(FPS_DECL) RPT8(FPS_LOAD) RPT8(FPS_PIN)
        for (int t = tid; t < N; t += T)
            sxyz[t] = make_float4(X[t], X[N+t], X[2*N+t], 0.f);
        float* NX_ = xyz1 + (size_t)bid * 3 * 1024;
        if (tid == 0){ NX_[0] = X[0]; NX_[1024] = X[N]; NX_[2048] = X[2*N]; }
        v2f l2x = (v2f){X[0], X[0]}, l2y = (v2f){X[N], X[N]}, l2z = (v2f){X[2*N], X[2*N]};
        __syncthreads();
        for (int i = 1; i < 512; ++i){
            unsigned long long bp = 0;
            RPT8(FPS_UPD)
            DPP_REDUCE2(bp)
            FPS_COMBINE(i)
            l2x = (v2f){wn.x, wn.x}; l2y = (v2f){wn.y, wn.y}; l2z = (v2f){wn.z, wn.z};
            if (tid == 0){ NX_[i] = wn.x; NX_[1024 + i] = wn.y; NX_[2048 + i] = wn.z; }
        }
        float* SV = fpssav + (size_t)bid * 4160;
        RPT8(FPS_SAVE)
        if (tid == 0){ SV[4096] = l2x.x; SV[4097] = l2y.x; SV[4098] = l2z.x; }
    } else if (bid < 520){
        int u = bid - 8;
        dev_knn4(u >> 6, (u & 63) << 6, xyz_in, 4096, xyz_in, 4096, idx4,
                 (float4*)LB, (unsigned long long (*)[33])(LB + 16384));
    } else if (bid < 548){
        int m = bid - 520;
        const float* s;
        if (m < 2) s = fn_wc + (size_t)m * 4096;
        else if (m < 4) s = fn_wg + (size_t)(m - 2) * 4096;
        else if (m < 16) s = res_wc + (size_t)(m - 4) * 4096;
        else s = res_wg + (size_t)(m - 16) * 4096;
        float* o = wT + (size_t)m * 4096;
        for (int t = tid; t < 4096; t += 256){
            int oo = t >> 6, dd = t & 63;
            o[dd * 64 + oo] = s[t];
        }
    } else {
        for (int t = bid - 548; t < 512; t += 64)
            dev_conv0(t, xyz_in, w0, dm4a, pm4a);
    }
}

// ================= LAUNCH 2: fps16[512,1024) || res4096#1 =================
__global__ void __launch_bounds__(256, 1)
k_frontb(const float* __restrict__ xyz_in, const float* __restrict__ wT,
         const float* __restrict__ dm4a, const float* __restrict__ pm4a,
         const int* __restrict__ idx4,
         float* __restrict__ dm4b, float* __restrict__ pm4b,
         float* __restrict__ xyz1, const float* __restrict__ fpssav){
    __shared__ __align__(16) char LB[66560];
    __shared__ unsigned long long sred[2][4];
    int bid = blockIdx.x, tid = threadIdx.x;
    if (bid < 8){
        float4* sxyz = (float4*)LB;
        constexpr int N = 4096, T = 256;
        const float* X = xyz_in + (size_t)bid * 3 * N;
        const float* SV = fpssav + (size_t)bid * 4160;
        RPT8(FPS_DECL) RPT8(FPS_LOAD) RPT8(FPS_PIN)
        RPT8(FPS_REST)
        for (int t = tid; t < N; t += T)
            sxyz[t] = make_float4(X[t], X[N+t], X[2*N+t], 0.f);
        float lx0 = SV[4096], ly0 = SV[4097], lz0 = SV[4098];
        v2f l2x = (v2f){lx0, lx0}, l2y = (v2f){ly0, ly0}, l2z = (v2f){lz0, lz0};
        float* NX_ = xyz1 + (size_t)bid * 3 * 1024;
        __syncthreads();
        for (int i = 512; i < 1024; ++i){
            unsigned long long bp = 0;
            RPT8(FPS_UPD)
            DPP_REDUCE2(bp)
            FPS_COMBINE(i)
            l2x = (v2f){wn.x, wn.x}; l2y = (v2f){wn.y, wn.y}; l2z = (v2f){wn.z, wn.z};
            if (tid == 0){ NX_[i] = wn.x; NX_[1024 + i] = wn.y; NX_[2048 + i] = wn.z; }
        }
    } else {
        for (int t = bid - 8; t < 512; t += 248)
            dev_res(t >> 6, (t & 63) << 6, 4096, dm4a, pm4a, idx4,
                    wT + 0 * 4096, wT + 2 * 4096, dm4b, pm4b, (float (*)[65])LB);
    }
}

// ================= LAUNCH 3: fps4 || res4096#2 || knn(1024,4096) || knn(1024,1024) =================
__global__ void __launch_bounds__(256, 1)
k_mid1(const float* __restrict__ xyz_in, const float* __restrict__ xyz1,
       const float* __restrict__ wT,
       const float* __restrict__ dm4b, const float* __restrict__ pm4b,
       const int* __restrict__ idx4,
       float* __restrict__ dm4a, float* __restrict__ pm4a,
       int* __restrict__ i1024p, int* __restrict__ i1024s,
       float* __restrict__ xyz2){
    __shared__ __align__(16) char LB[33280];
    __shared__ unsigned long long sred[2][4];
    int bid = blockIdx.x, tid = threadIdx.x;
    if (bid < 8){
        float4* sxyz = (float4*)LB;
        constexpr int N = 1024, T = 256;
        const float* X = xyz1 + (size_t)bid * 3 * N;
        FPS_DECL(0) FPS_DECL(1)
        FPS_LOAD(0) FPS_LOAD(1) FPS_PIN(0) FPS_PIN(1)
        for (int t = tid; t < N; t += T)
            sxyz[t] = make_float4(X[t], X[N+t], X[2*N+t], 0.f);
        float* NX_ = xyz2 + (size_t)bid * 3 * 256;
        if (tid == 0){ NX_[0] = X[0]; NX_[256] = X[N]; NX_[512] = X[2*N]; }
        v2f l2x = (v2f){X[0], X[0]}, l2y = (v2f){X[N], X[N]}, l2z = (v2f){X[2*N], X[2*N]};
        __syncthreads();
        for (int i = 1; i < 256; ++i){
            unsigned long long bp = 0;
            FPS_UPD(0) FPS_UPD(1)
            DPP_REDUCE2(bp)
            FPS_COMBINE(i)
            l2x = (v2f){wn.x, wn.x}; l2y = (v2f){wn.y, wn.y}; l2z = (v2f){wn.z, wn.z};
            if (tid == 0){ NX_[i] = wn.x; NX_[256 + i] = wn.y; NX_[512 + i] = wn.z; }
        }
    } else if (bid < 520){
        int t = bid - 8;
        dev_res(t >> 6, (t & 63) << 6, 4096, dm4b, pm4b, idx4,
                wT + 1 * 4096, wT + 3 * 4096, dm4a, pm4a, (float (*)[65])LB);
    } else if (bid < 648){
        int u = bid - 520;
        dev_knn4(u >> 4, (u & 15) << 6, xyz1, 1024, xyz_in, 4096, i1024p,
                 (float4*)LB, (unsigned long long (*)[33])(LB + 16384));
    } else {
        int u = bid - 648;
        dev_knn4(u >> 4, (u & 15) << 6, xyz1, 1024, xyz1, 1024, i1024s,
                 (float4*)LB, (unsigned long long (*)[33])(LB + 16384));
    }
}

// ================= LAUNCH 4: fps1 || pool1024 || knn(256,1024) || knn(256,256) =================
__global__ void __launch_bounds__(256, 1)
k_mid2(const float* __restrict__ xyz1, const float* __restrict__ xyz2,
       const float* __restrict__ pm4a, const int* __restrict__ i1024p,
       float* __restrict__ dm1a, float* __restrict__ pm1a,
       int* __restrict__ i256p, int* __restrict__ i256s,
       float* __restrict__ xyz3){
    __shared__ __align__(16) char LB[33280];
    __shared__ unsigned long long sred[2][4];
    int bid = blockIdx.x, tid = threadIdx.x;
    if (bid < 8){
        float4* sxyz = (float4*)LB;
        const float* X2 = xyz2 + (size_t)bid * 3 * 256;
        for (int t = tid; t < 256; t += 256)
            sxyz[t] = make_float4(X2[t], X2[256 + t], X2[512 + t], 0.f);
        float s1x = X2[tid], s1y = X2[256 + tid], s1z = X2[512 + tid], s1d = 1e10f;
        asm volatile("" : "+v"(s1x), "+v"(s1y), "+v"(s1z));
        float* NX_ = xyz3 + (size_t)bid * 3 * 64;
        if (tid == 0){ NX_[0] = X2[0]; NX_[64] = X2[256]; NX_[128] = X2[512]; }
        float lx = X2[0], ly = X2[256], lz = X2[512];
        __syncthreads();
        for (int i = 1; i < 64; ++i){
            float dx = s1x - lx, dy = s1y - ly, dz = s1z - lz;
            float dd = fmaf(dz, dz, fmaf(dy, dy, dx*dx));
            float nd = fminf(s1d, dd); s1d = nd;
            unsigned long long bp = ((unsigned long long)__float_as_uint(nd) << 32) | (unsigned)~tid;
            DPP_REDUCE2(bp)
            FPS_COMBINE(i)
            lx = wn.x; ly = wn.y; lz = wn.z;
            if (tid == 0){ NX_[i] = wn.x; NX_[64 + i] = wn.y; NX_[128 + i] = wn.z; }
        }
    } else if (bid < 136){
        int u = bid - 8;
        dev_pool(u >> 4, (u & 15) << 6, 1024, 4096, pm4a, i1024p,
                 dm1a, pm1a, (float (*)[65])LB);
    } else if (bid < 168){
        int u = bid - 136;
        dev_knn4(u >> 2, (u & 3) << 6, xyz2, 256, xyz1, 1024, i256p,
                 (float4*)LB, (unsigned long long (*)[33])(LB + 16384));
    } else {
        int u = bid - 168;
        dev_knn4(u >> 2, (u & 3) << 6, xyz2, 256, xyz2, 256, i256s,
                 (float4*)LB, (unsigned long long (*)[33])(LB + 16384));
    }
}

// ================= LAUNCH 5: res1024#1 || knn(64,256) || knn(64,64) =================
__global__ void __launch_bounds__(256, 1)
k_mid3(const float* __restrict__ xyz2, const float* __restrict__ xyz3,
       const float* __restrict__ dm1a, const float* __restrict__ pm1a,
       const int* __restrict__ i1024s, const float* __restrict__ wT,
       float* __restrict__ dm1b, float* __restrict__ pm1b,
       int* __restrict__ i64p, int* __restrict__ i64s){
    __shared__ __align__(16) char LB[33280];
    int bid = blockIdx.x;
    if (bid < 128){
        dev_res(bid >> 4, (bid & 15) << 6, 1024, dm1a, pm1a, i1024s,
                wT + 4 * 4096, wT + 16 * 4096, dm1b, pm1b, (float (*)[65])LB);
    } else if (bid < 136){
        dev_knn4(bid - 128, 0, xyz3, 64, xyz2, 256, i64p,
                 (float4*)LB, (unsigned long long (*)[33])(LB + 16384));
    } else {
        dev_knn4(bid - 136, 0, xyz3, 64, xyz3, 64, i64s,
                 (float4*)LB, (unsigned long long (*)[33])(LB + 16384));
    }
}

// ================= generic res / pool launches =================
__global__ void __launch_bounds__(256, 1)
k_res_g(const float* __restrict__ dmc, const float* __restrict__ pmc,
        const int* __restrict__ idx, const float* __restrict__ wc_,
        const float* __restrict__ wg_, float* __restrict__ dmo,
        float* __restrict__ pmo, int n){
    __shared__ float tile[64][65];
    int tiles = n >> 6;
    int b = blockIdx.x / tiles, j0 = (blockIdx.x % tiles) << 6;
    dev_res(b, j0, n, dmc, pmc, idx, wc_, wg_, dmo, pmo, tile);
}

__global__ void __launch_bounds__(256, 1)
k_pool_g(const float* __restrict__ pmc, const int* __restrict__ idx,
         float* __restrict__ dmo, float* __restrict__ pmo, int np, int nsrc){
    __shared__ float tile[64][65];
    int tiles = np >> 6;
    int b = blockIdx.x / tiles, m0 = (blockIdx.x % tiles) << 6;
    dev_pool(b, m0, np, nsrc, pmc, idx, dmo, pmo, tile);
}

// ================= tail: pool64 + 4x res64 (in-LDS) + final =================
#define RC_FINL64(i) a##i = a##i * inv + pmX[lane][w16 + (i)];
#define RC_WL64(i)   pmX[lane][w16 + (i)] = a##i;

__device__ __forceinline__ void res_lds64g(float (*pmX)[65], float (*S)[65],
        const int* idg, const float* __restrict__ wcT, const float* __restrict__ wgT,
        int lane, int w){
    for (int c = 0; c < 16; ++c){
        int col = w * 16 + c;
        const int* id = idg + col * 8;
        float v = 0.f;
        #pragma unroll
        for (int k = 0; k < 8; ++k) v += leaky(pmX[id[k]][lane]);
        S[col][lane] = v;
    }
    __syncthreads();
    int w16 = w * 16;
    RPT16(RC_DECL)
    #pragma unroll 2
    for (int d = 0; d < 64; ++d){
        float h  = leaky(pmX[lane][d]);
        float sv = S[lane][d];
        const float* wc = wcT + d * 64 + w16;
        const float* wg = wgT + d * 64 + w16;
        RPT16(RC_FMA)
    }
    const float inv = 1.0f / 9.0f;
    RPT16(RC_FINL64)
    __syncthreads();
    RPT16(RC_WL64)
    __syncthreads();
}

__global__ void __launch_bounds__(256, 1)
k_tail64(const float* __restrict__ pm2a, const int* __restrict__ i64p,
         const int* __restrict__ i64s, const float* __restrict__ wT,
         const float* __restrict__ wl, float* __restrict__ out){
    __shared__ float pm64[64][65];
    __shared__ float S64[64][65];
    int b = blockIdx.x, tid = threadIdx.x;
    int lane = tid & 63, w = tid >> 6;
    const float* PM = pm2a + (size_t)b * 256 * 64;
    const int* idp = i64p + (size_t)b * 64 * 8;
    for (int c = 0; c < 16; ++c){
        int col = w * 16 + c;
        const int* id = idp + col * 8;
        float v = -FLT_MAX;
        #pragma unroll
        for (int k = 0; k < 8; ++k)
            v = fmaxf(v, PM[(size_t)id[k] * 64 + lane]);
        pm64[col][lane] = v;
    }
    __syncthreads();
    const int* ids = i64s + (size_t)b * 64 * 8;
    for (int L = 0; L < 4; ++L)
        res_lds64g(pm64, S64, ids, wT + (size_t)(12 + L) * 4096,
                   wT + (size_t)(24 + L) * 4096, lane, w);
    if (tid < 64){
        float acc = 0.f;
        for (int d = 0; d < 64; ++d) acc += wl[d] * leaky(pm64[tid][d]);
        out[(size_t)b * 64 + tid] = acc;
    }
}

extern "C" void kernel_launch(void* const* d_in, const int* in_sizes, int n_in,
                              void* d_out, int out_size, void* d_ws, size_t ws_size,
                              hipStream_t stream){
    const float* xyz_in  = (const float*)d_in[0];
    const float* w0      = (const float*)d_in[1];
    const float* fn_wc   = (const float*)d_in[2];
    const float* fn_wg   = (const float*)d_in[3];
    const float* res_wc  = (const float*)d_in[4];
    const float* res_wg  = (const float*)d_in[5];
    const float* w_last  = (const float*)d_in[6];
    float* out = (float*)d_out;
    char* ws = (char*)d_ws;

    float* wT    = (float*)(ws + 0UL);
    float* dm4a  = (float*)(ws + 458752UL);
    float* dm4b  = (float*)(ws + 8847360UL);
    float* pm4a  = (float*)(ws + 17235968UL);
    float* pm4b  = (float*)(ws + 25624576UL);
    int*   idx4  = (int*)  (ws + 34013184UL);
    float* xyz1  = (float*)(ws + 35061760UL);
    float* xyz2  = (float*)(ws + 35160064UL);
    float* xyz3  = (float*)(ws + 35184640UL);
    int* i1024p  = (int*)(ws + 35190784UL);
    int* i1024s  = (int*)(ws + 35452928UL);
    int* i256p   = (int*)(ws + 35715072UL);
    int* i256s   = (int*)(ws + 35780608UL);
    int* i64p    = (int*)(ws + 35846144UL);
    int* i64s    = (int*)(ws + 35862528UL);
    float* fpssav = (float*)(ws + 35878912UL);
    float* dm1a = (float*)((char*)dm4b + 0UL);
    float* dm1b = (float*)((char*)dm4b + 2097152UL);
    float* dm2a = (float*)((char*)dm4b + 4194304UL);
    float* dm2b = (float*)((char*)dm4b + 4718592UL);
    float* pm1a = (float*)((char*)pm4b + 0UL);
    float* pm1b = (float*)((char*)pm4b + 2097152UL);
    float* pm2a = (float*)((char*)pm4b + 4194304UL);
    float* pm2b = (float*)((char*)pm4b + 4718592UL);

    // L1: fps16[1,512) || knn@4096(split) || transpose || conv0
    k_front<<<612, 256, 0, stream>>>(xyz_in, w0, fn_wc, fn_wg, res_wc, res_wg,
                                     wT, dm4a, pm4a, idx4, xyz1, fpssav);
    // L2: fps16[512,1024) || res4096#1
    k_frontb<<<256, 256, 0, stream>>>(xyz_in, wT, dm4a, pm4a, idx4,
                                      dm4b, pm4b, xyz1, fpssav);
    // L3: fps4 || res4096#2 || knn(1024,4096) || knn(1024,1024)
    k_mid1<<<776, 256, 0, stream>>>(xyz_in, xyz1, wT, dm4b, pm4b, idx4,
                                    dm4a, pm4a, i1024p, i1024s, xyz2);
    // L4: fps1 || pool1024 || knn(256,1024) || knn(256,256)
    k_mid2<<<200, 256, 0, stream>>>(xyz1, xyz2, pm4a, i1024p, dm1a, pm1a,
                                    i256p, i256s, xyz3);
    // L5: res1024#1 || knn(64,256) || knn(64,64)
    k_mid3<<<144, 256, 0, stream>>>(xyz2, xyz3, dm1a, pm1a, i1024s, wT,
                                    dm1b, pm1b, i64p, i64s);
    // L6-8: res@1024 #2-#4
    k_res_g<<<128, 256, 0, stream>>>(dm1b, pm1b, i1024s, wT + 5*4096, wT + 17*4096, dm1a, pm1a, 1024);
    k_res_g<<<128, 256, 0, stream>>>(dm1a, pm1a, i1024s, wT + 6*4096, wT + 18*4096, dm1b, pm1b, 1024);
    k_res_g<<<128, 256, 0, stream>>>(dm1b, pm1b, i1024s, wT + 7*4096, wT + 19*4096, dm1a, pm1a, 1024);
    // L9: pool@256
    k_pool_g<<<32, 256, 0, stream>>>(pm1a, i256p, dm2a, pm2a, 256, 1024);
    // L10-13: res@256 x4
    k_res_g<<<32, 256, 0, stream>>>(dm2a, pm2a, i256s, wT + 8*4096,  wT + 20*4096, dm2b, pm2b, 256);
    k_res_g<<<32, 256, 0, stream>>>(dm2b, pm2b, i256s, wT + 9*4096,  wT + 21*4096, dm2a, pm2a, 256);
    k_res_g<<<32, 256, 0, stream>>>(dm2a, pm2a, i256s, wT + 10*4096, wT + 22*4096, dm2b, pm2b, 256);
    k_res_g<<<32, 256, 0, stream>>>(dm2b, pm2b, i256s, wT + 11*4096, wT + 23*4096, dm2a, pm2a, 256);
    // L14: pool64 + res@64 x4 + final
    k_tail64<<<8, 256, 0, stream>>>(pm2a, i64p, i64s, wT, w_last, out);
}